// Round 1
// baseline (20334.244 us; speedup 1.0000x reference)
//
#include <hip/hip_runtime.h>
#include <math.h>

#define BATCH    4
#define SEQLEN   4096
#define INPUT_DIM 3
#define OUTPUT_DIM 4
#define D_MODEL  192
#define D_INNER  384
#define NHEADS   8
#define HEADDIM  48
#define D_STATE  64
#define CONV_DIM 512        /* D_INNER + 2*D_STATE */
#define D_IN_PROJ 904       /* 2*D_INNER + 2*D_STATE + NHEADS */
#define D_CONV   4
#define NLAYERS  8
#define ROWS     (BATCH*SEQLEN)   /* 16384 */

/* scan n-split: each block owns NPER of the 64 state columns */
#define NCHUNK 4
#define NPER   16

/* ---------------- K1: input linear + relu -> z (B,L,192) ---------------- */
__global__ void k_lin_in(const float* __restrict__ inp, const float* __restrict__ w,
                         const float* __restrict__ b, float* __restrict__ z) {
  int tid = blockIdx.x * blockDim.x + threadIdx.x;
  if (tid >= ROWS * D_MODEL) return;
  int d   = tid % D_MODEL;
  int row = tid / D_MODEL;
  int bb  = row / SEQLEN, l = row % SEQLEN;
  float acc = b[d];
#pragma unroll
  for (int i = 0; i < INPUT_DIM; i++)
    acc += inp[(size_t)(bb * INPUT_DIM + i) * SEQLEN + l] * w[d * INPUT_DIM + i];
  z[tid] = fmaxf(acc, 0.f);
}

/* ------------- shared GEMM: C[M][N] = A[M][K] @ B[N][K]^T --------------- */
/* M % 64 == 0, K % 16 == 0, N guarded. 64x64 tile, BK=16, 4x4 per thread. */
__global__ __launch_bounds__(256) void k_gemm_abt(const float* __restrict__ A,
                                                  const float* __restrict__ B,
                                                  float* __restrict__ C,
                                                  int M, int N, int K) {
  __shared__ __align__(16) float As[16][68];
  __shared__ __align__(16) float Bs[16][68];
  int tid = threadIdx.x;
  int m0 = blockIdx.x * 64, n0 = blockIdx.y * 64;
  int lr = tid >> 2;            /* 0..63 tile row */
  int lk = (tid & 3) << 2;      /* 0,4,8,12       */
  int tx = tid & 15, ty = tid >> 4;
  float acc[4][4] = {};
  for (int kt = 0; kt < K; kt += 16) {
    float4 av = *(const float4*)&A[(size_t)(m0 + lr) * K + kt + lk];
    As[lk + 0][lr] = av.x; As[lk + 1][lr] = av.y;
    As[lk + 2][lr] = av.z; As[lk + 3][lr] = av.w;
    float4 bv = make_float4(0.f, 0.f, 0.f, 0.f);
    if (n0 + lr < N) bv = *(const float4*)&B[(size_t)(n0 + lr) * K + kt + lk];
    Bs[lk + 0][lr] = bv.x; Bs[lk + 1][lr] = bv.y;
    Bs[lk + 2][lr] = bv.z; Bs[lk + 3][lr] = bv.w;
    __syncthreads();
#pragma unroll
    for (int k = 0; k < 16; k++) {
      float4 a4 = *(const float4*)&As[k][ty << 2];
      float4 b4 = *(const float4*)&Bs[k][tx << 2];
      acc[0][0] = fmaf(a4.x, b4.x, acc[0][0]); acc[0][1] = fmaf(a4.x, b4.y, acc[0][1]);
      acc[0][2] = fmaf(a4.x, b4.z, acc[0][2]); acc[0][3] = fmaf(a4.x, b4.w, acc[0][3]);
      acc[1][0] = fmaf(a4.y, b4.x, acc[1][0]); acc[1][1] = fmaf(a4.y, b4.y, acc[1][1]);
      acc[1][2] = fmaf(a4.y, b4.z, acc[1][2]); acc[1][3] = fmaf(a4.y, b4.w, acc[1][3]);
      acc[2][0] = fmaf(a4.z, b4.x, acc[2][0]); acc[2][1] = fmaf(a4.z, b4.y, acc[2][1]);
      acc[2][2] = fmaf(a4.z, b4.z, acc[2][2]); acc[2][3] = fmaf(a4.z, b4.w, acc[2][3]);
      acc[3][0] = fmaf(a4.w, b4.x, acc[3][0]); acc[3][1] = fmaf(a4.w, b4.y, acc[3][1]);
      acc[3][2] = fmaf(a4.w, b4.z, acc[3][2]); acc[3][3] = fmaf(a4.w, b4.w, acc[3][3]);
    }
    __syncthreads();
  }
  int m = m0 + (ty << 2), n = n0 + (tx << 2);
#pragma unroll
  for (int i = 0; i < 4; i++)
#pragma unroll
    for (int j = 0; j < 4; j++)
      if (n + j < N) C[(size_t)(m + i) * N + n + j] = acc[i][j];
}

/* ---------- K3: depthwise causal conv (4 taps) + silu -> xc ------------- */
__global__ void k_conv(const float* __restrict__ zx, const float* __restrict__ cw,
                       const float* __restrict__ cb, float* __restrict__ xc) {
  int tid = blockIdx.x * blockDim.x + threadIdx.x;
  if (tid >= ROWS * CONV_DIM) return;
  int c   = tid % CONV_DIM;
  int row = tid / CONV_DIM;
  int b = row / SEQLEN, l = row % SEQLEN;
  float acc = cb[c];
#pragma unroll
  for (int k = 0; k < D_CONV; k++) {
    int t = l + k - (D_CONV - 1);
    if (t >= 0)
      acc += zx[(size_t)(b * SEQLEN + t) * D_IN_PROJ + D_INNER + c] * cw[c * D_CONV + k];
  }
  xc[tid] = acc / (1.f + expf(-acc));   /* silu */
}

/* --------------------- K4: sequential selective scan -------------------- */
/* grid = BATCH*NHEADS*NCHUNK blocks of 64 threads (1 wave).                */
/* lane = p (0..47 active); block owns n in [c*NPER, c*NPER+NPER).          */
#define SCAN_LOAD(T, BV, CV, XV, DR)                                          \
  do { int _t = (T);                                                         \
    if (_t < SEQLEN) {                                                       \
      const float* _base = xcb + (size_t)_t * CONV_DIM;                      \
      _Pragma("unroll")                                                      \
      for (int _j = 0; _j < NPER; _j += 4) {                                 \
        *(float4*)&BV[_j] = *(const float4*)(_base + D_INNER + n0 + _j);     \
        *(float4*)&CV[_j] = *(const float4*)(_base + D_INNER + D_STATE + n0 + _j); \
      }                                                                      \
      XV = _base[h * HEADDIM + p];                                           \
      DR = zxb[(size_t)_t * D_IN_PROJ + (D_INNER + CONV_DIM) + h];           \
    }                                                                        \
  } while (0)

#define SCAN_STEP(T, BV, CV, XV, DR)                                          \
  do {                                                                        \
    float _dts = DR + dtb;                                                    \
    float _dtv = _dts > 20.f ? _dts : log1pf(expf(_dts));                     \
    float _dec = expf(_dtv * Aneg);                                           \
    float _dtx = _dtv * XV;                                                   \
    float _y0 = 0.f, _y1 = 0.f, _y2 = 0.f, _y3 = 0.f;                         \
    _Pragma("unroll")                                                         \
    for (int _j = 0; _j < NPER; _j += 4) {                                    \
      hst[_j+0] = fmaf(hst[_j+0], _dec, _dtx * BV[_j+0]); _y0 = fmaf(hst[_j+0], CV[_j+0], _y0); \
      hst[_j+1] = fmaf(hst[_j+1], _dec, _dtx * BV[_j+1]); _y1 = fmaf(hst[_j+1], CV[_j+1], _y1); \
      hst[_j+2] = fmaf(hst[_j+2], _dec, _dtx * BV[_j+2]); _y2 = fmaf(hst[_j+2], CV[_j+2], _y2); \
      hst[_j+3] = fmaf(hst[_j+3], _dec, _dtx * BV[_j+3]); _y3 = fmaf(hst[_j+3], CV[_j+3], _y3); \
    }                                                                         \
    float _y = (_y0 + _y1) + (_y2 + _y3);                                     \
    if (cchunk == 0) _y = fmaf(Dh, XV, _y);                                   \
    if (act) yb[(size_t)(T) * D_INNER] = _y;                                  \
  } while (0)

__global__ __launch_bounds__(64) void k_scan(const float* __restrict__ zx,
                                             const float* __restrict__ xc,
                                             const float* __restrict__ dt_bias,
                                             const float* __restrict__ A_log,
                                             const float* __restrict__ Dp,
                                             float* __restrict__ ypart) {
  int blk = blockIdx.x;
  int cchunk = blk % NCHUNK;
  int bh = blk / NCHUNK;
  int h = bh % NHEADS, b = bh / NHEADS;
  int p = threadIdx.x;
  bool act = p < HEADDIM;
  float Aneg = -expf(A_log[h]);
  float dtb  = dt_bias[h];
  float Dh   = Dp[h];
  int n0 = cchunk * NPER;
  const float* xcb = xc + (size_t)b * SEQLEN * CONV_DIM;
  const float* zxb = zx + (size_t)b * SEQLEN * D_IN_PROJ;
  float* yb = ypart + ((size_t)cchunk * ROWS + (size_t)b * SEQLEN) * D_INNER + h * HEADDIM + p;

  float hst[NPER];
#pragma unroll
  for (int j = 0; j < NPER; j++) hst[j] = 0.f;

  float Ba[NPER], Ca[NPER], xa = 0.f, da = 0.f;
  float Bb[NPER], Cb[NPER], xb = 0.f, db = 0.f;
  SCAN_LOAD(0, Ba, Ca, xa, da);
  for (int t = 0; t < SEQLEN; t += 2) {
    SCAN_LOAD(t + 1, Bb, Cb, xb, db);
    SCAN_STEP(t, Ba, Ca, xa, da);
    SCAN_LOAD(t + 2, Ba, Ca, xa, da);
    SCAN_STEP(t + 1, Bb, Cb, xb, db);
  }
}

/* ---------- K5a: sum partials, gate with silu(z), RMSNorm --------------- */
__global__ __launch_bounds__(128) void k_gate_rms(const float* __restrict__ ypart,
                                                  const float* __restrict__ zx,
                                                  const float* __restrict__ nw,
                                                  float* __restrict__ ynorm) {
  int row = blockIdx.x;
  int tid = threadIdx.x;
  float v[3];
  float ssq = 0.f;
#pragma unroll
  for (int j = 0; j < 3; j++) {
    int e = tid + j * 128;
    float s = 0.f;
#pragma unroll
    for (int cc = 0; cc < NCHUNK; cc++)
      s += ypart[((size_t)cc * ROWS + row) * D_INNER + e];
    float zr = zx[(size_t)row * D_IN_PROJ + e];
    s *= zr / (1.f + expf(-zr));
    v[j] = s;
    ssq += s * s;
  }
#pragma unroll
  for (int o = 32; o > 0; o >>= 1) ssq += __shfl_down(ssq, o);
  __shared__ float red[2];
  if ((tid & 63) == 0) red[tid >> 6] = ssq;
  __syncthreads();
  float inv = rsqrtf((red[0] + red[1]) * (1.f / D_INNER) + 1e-5f);
#pragma unroll
  for (int j = 0; j < 3; j++) {
    int e = tid + j * 128;
    ynorm[(size_t)row * D_INNER + e] = v[j] * inv * nw[e];
  }
}

/* -------------- K5c: residual add + LayerNorm (in place on z) ----------- */
__global__ __launch_bounds__(64) void k_res_ln(const float* __restrict__ tin,
                                               float* zio,
                                               const float* __restrict__ lnw,
                                               const float* __restrict__ lnb) {
  int row = blockIdx.x;
  int tid = threadIdx.x;
  size_t base = (size_t)row * D_MODEL;
  float v0 = tin[base + tid]       + zio[base + tid];
  float v1 = tin[base + tid + 64]  + zio[base + tid + 64];
  float v2 = tin[base + tid + 128] + zio[base + tid + 128];
  float s = v0 + v1 + v2;
#pragma unroll
  for (int o = 32; o > 0; o >>= 1) s += __shfl_down(s, o);
  float mu = __shfl(s, 0) * (1.f / D_MODEL);
  float d0 = v0 - mu, d1 = v1 - mu, d2 = v2 - mu;
  float q = d0 * d0 + d1 * d1 + d2 * d2;
#pragma unroll
  for (int o = 32; o > 0; o >>= 1) q += __shfl_down(q, o);
  float inv = rsqrtf(__shfl(q, 0) * (1.f / D_MODEL) + 1e-5f);
  zio[base + tid]       = d0 * inv * lnw[tid]       + lnb[tid];
  zio[base + tid + 64]  = d1 * inv * lnw[tid + 64]  + lnb[tid + 64];
  zio[base + tid + 128] = d2 * inv * lnw[tid + 128] + lnb[tid + 128];
}

/* ------------- K6: output linear + transpose to (B, 4, L) --------------- */
__global__ void k_lin_out(const float* __restrict__ z, const float* __restrict__ w,
                          const float* __restrict__ bias, float* __restrict__ out) {
  int tid = blockIdx.x * blockDim.x + threadIdx.x;
  if (tid >= ROWS) return;
  int b = tid / SEQLEN, l = tid % SEQLEN;
  float acc0 = bias[0], acc1 = bias[1], acc2 = bias[2], acc3 = bias[3];
  const float* zr = z + (size_t)tid * D_MODEL;
  for (int d = 0; d < D_MODEL; d += 4) {
    float4 zv = *(const float4*)&zr[d];
    acc0 = fmaf(zv.x, w[0 * D_MODEL + d], acc0); acc0 = fmaf(zv.y, w[0 * D_MODEL + d + 1], acc0);
    acc0 = fmaf(zv.z, w[0 * D_MODEL + d + 2], acc0); acc0 = fmaf(zv.w, w[0 * D_MODEL + d + 3], acc0);
    acc1 = fmaf(zv.x, w[1 * D_MODEL + d], acc1); acc1 = fmaf(zv.y, w[1 * D_MODEL + d + 1], acc1);
    acc1 = fmaf(zv.z, w[1 * D_MODEL + d + 2], acc1); acc1 = fmaf(zv.w, w[1 * D_MODEL + d + 3], acc1);
    acc2 = fmaf(zv.x, w[2 * D_MODEL + d], acc2); acc2 = fmaf(zv.y, w[2 * D_MODEL + d + 1], acc2);
    acc2 = fmaf(zv.z, w[2 * D_MODEL + d + 2], acc2); acc2 = fmaf(zv.w, w[2 * D_MODEL + d + 3], acc2);
    acc3 = fmaf(zv.x, w[3 * D_MODEL + d], acc3); acc3 = fmaf(zv.y, w[3 * D_MODEL + d + 1], acc3);
    acc3 = fmaf(zv.z, w[3 * D_MODEL + d + 2], acc3); acc3 = fmaf(zv.w, w[3 * D_MODEL + d + 3], acc3);
  }
  out[((size_t)b * OUTPUT_DIM + 0) * SEQLEN + l] = acc0;
  out[((size_t)b * OUTPUT_DIM + 1) * SEQLEN + l] = acc1;
  out[((size_t)b * OUTPUT_DIM + 2) * SEQLEN + l] = acc2;
  out[((size_t)b * OUTPUT_DIM + 3) * SEQLEN + l] = acc3;
}

/* ------------------------------- launch --------------------------------- */
extern "C" void kernel_launch(void* const* d_in, const int* in_sizes, int n_in,
                              void* d_out, int out_size, void* d_ws, size_t ws_size,
                              hipStream_t stream) {
  const float* inp       = (const float*)d_in[0];
  const float* lin_in_w  = (const float*)d_in[1];
  const float* lin_in_b  = (const float*)d_in[2];
  const float* in_w      = (const float*)d_in[3];
  const float* conv_w    = (const float*)d_in[4];
  const float* conv_b    = (const float*)d_in[5];
  const float* dt_bias   = (const float*)d_in[6];
  const float* A_log     = (const float*)d_in[7];
  const float* Dmat      = (const float*)d_in[8];
  const float* norm_w    = (const float*)d_in[9];
  const float* out_w     = (const float*)d_in[10];
  const float* ln_w      = (const float*)d_in[11];
  const float* ln_b      = (const float*)d_in[12];
  const float* lin_out_w = (const float*)d_in[13];
  const float* lin_out_b = (const float*)d_in[14];
  float* out = (float*)d_out;

  float* ws = (float*)d_ws;
  size_t off = 0;
  float* z     = ws + off; off += (size_t)ROWS * D_MODEL;
  float* zx    = ws + off; off += (size_t)ROWS * D_IN_PROJ;
  float* xc    = ws + off; off += (size_t)ROWS * CONV_DIM;
  float* ypart = ws + off; off += (size_t)NCHUNK * ROWS * D_INNER;
  float* ynorm = ws + off; off += (size_t)ROWS * D_INNER;
  float* tmp   = ws + off; off += (size_t)ROWS * D_MODEL;

  k_lin_in<<<(ROWS * D_MODEL + 255) / 256, 256, 0, stream>>>(inp, lin_in_w, lin_in_b, z);

  for (int i = 0; i < NLAYERS; i++) {
    k_gemm_abt<<<dim3(ROWS / 64, (D_IN_PROJ + 63) / 64), 256, 0, stream>>>(
        z, in_w + (size_t)i * D_IN_PROJ * D_MODEL, zx, ROWS, D_IN_PROJ, D_MODEL);
    k_conv<<<(ROWS * CONV_DIM + 255) / 256, 256, 0, stream>>>(
        zx, conv_w + (size_t)i * CONV_DIM * D_CONV, conv_b + (size_t)i * CONV_DIM, xc);
    k_scan<<<BATCH * NHEADS * NCHUNK, 64, 0, stream>>>(
        zx, xc, dt_bias + i * NHEADS, A_log + i * NHEADS, Dmat + i * NHEADS, ypart);
    k_gate_rms<<<ROWS, 128, 0, stream>>>(ypart, zx, norm_w + (size_t)i * D_INNER, ynorm);
    k_gemm_abt<<<dim3(ROWS / 64, (D_MODEL + 63) / 64), 256, 0, stream>>>(
        ynorm, out_w + (size_t)i * D_MODEL * D_INNER, tmp, ROWS, D_MODEL, D_INNER);
    k_res_ln<<<ROWS, 64, 0, stream>>>(tmp, z, ln_w + (size_t)i * D_MODEL, ln_b + (size_t)i * D_MODEL);
  }

  k_lin_out<<<(ROWS + 255) / 256, 256, 0, stream>>>(z, lin_out_w, lin_out_b, out);
}

// Round 2
// 5050.716 us; speedup vs baseline: 4.0260x; 4.0260x over previous
//
#include <hip/hip_runtime.h>
#include <math.h>

#define BATCH    4
#define SEQLEN   4096
#define INPUT_DIM 3
#define OUTPUT_DIM 4
#define D_MODEL  192
#define D_INNER  384
#define NHEADS   8
#define HEADDIM  48
#define D_STATE  64
#define CONV_DIM 512        /* D_INNER + 2*D_STATE */
#define D_IN_PROJ 904       /* 2*D_INNER + 2*D_STATE + NHEADS */
#define D_CONV   4
#define NLAYERS  8
#define ROWS     (BATCH*SEQLEN)   /* 16384 */

#define Q     128                 /* scan chunk length */
#define NCHK  (SEQLEN/Q)          /* 32 chunks */
#define SSIZE (HEADDIM*D_STATE)   /* 3072 per-chunk state */

/* ---------------- K1: input linear + relu -> z (B,L,192) ---------------- */
__global__ void k_lin_in(const float* __restrict__ inp, const float* __restrict__ w,
                         const float* __restrict__ b, float* __restrict__ z) {
  int tid = blockIdx.x * blockDim.x + threadIdx.x;
  if (tid >= ROWS * D_MODEL) return;
  int d   = tid % D_MODEL;
  int row = tid / D_MODEL;
  int bb  = row / SEQLEN, l = row % SEQLEN;
  float acc = b[d];
#pragma unroll
  for (int i = 0; i < INPUT_DIM; i++)
    acc += inp[(size_t)(bb * INPUT_DIM + i) * SEQLEN + l] * w[d * INPUT_DIM + i];
  z[tid] = fmaxf(acc, 0.f);
}

/* ------------- shared GEMM: C[M][N] = A[M][K] @ B[N][K]^T --------------- */
__global__ __launch_bounds__(256) void k_gemm_abt(const float* __restrict__ A,
                                                  const float* __restrict__ B,
                                                  float* __restrict__ C,
                                                  int M, int N, int K) {
  __shared__ __align__(16) float As[16][68];
  __shared__ __align__(16) float Bs[16][68];
  int tid = threadIdx.x;
  int m0 = blockIdx.x * 64, n0 = blockIdx.y * 64;
  int lr = tid >> 2;
  int lk = (tid & 3) << 2;
  int tx = tid & 15, ty = tid >> 4;
  float acc[4][4] = {};
  for (int kt = 0; kt < K; kt += 16) {
    float4 av = *(const float4*)&A[(size_t)(m0 + lr) * K + kt + lk];
    As[lk + 0][lr] = av.x; As[lk + 1][lr] = av.y;
    As[lk + 2][lr] = av.z; As[lk + 3][lr] = av.w;
    float4 bv = make_float4(0.f, 0.f, 0.f, 0.f);
    if (n0 + lr < N) bv = *(const float4*)&B[(size_t)(n0 + lr) * K + kt + lk];
    Bs[lk + 0][lr] = bv.x; Bs[lk + 1][lr] = bv.y;
    Bs[lk + 2][lr] = bv.z; Bs[lk + 3][lr] = bv.w;
    __syncthreads();
#pragma unroll
    for (int k = 0; k < 16; k++) {
      float4 a4 = *(const float4*)&As[k][ty << 2];
      float4 b4 = *(const float4*)&Bs[k][tx << 2];
      acc[0][0] = fmaf(a4.x, b4.x, acc[0][0]); acc[0][1] = fmaf(a4.x, b4.y, acc[0][1]);
      acc[0][2] = fmaf(a4.x, b4.z, acc[0][2]); acc[0][3] = fmaf(a4.x, b4.w, acc[0][3]);
      acc[1][0] = fmaf(a4.y, b4.x, acc[1][0]); acc[1][1] = fmaf(a4.y, b4.y, acc[1][1]);
      acc[1][2] = fmaf(a4.y, b4.z, acc[1][2]); acc[1][3] = fmaf(a4.y, b4.w, acc[1][3]);
      acc[2][0] = fmaf(a4.z, b4.x, acc[2][0]); acc[2][1] = fmaf(a4.z, b4.y, acc[2][1]);
      acc[2][2] = fmaf(a4.z, b4.z, acc[2][2]); acc[2][3] = fmaf(a4.z, b4.w, acc[2][3]);
      acc[3][0] = fmaf(a4.w, b4.x, acc[3][0]); acc[3][1] = fmaf(a4.w, b4.y, acc[3][1]);
      acc[3][2] = fmaf(a4.w, b4.z, acc[3][2]); acc[3][3] = fmaf(a4.w, b4.w, acc[3][3]);
    }
    __syncthreads();
  }
  int m = m0 + (ty << 2), n = n0 + (tx << 2);
#pragma unroll
  for (int i = 0; i < 4; i++)
#pragma unroll
    for (int j = 0; j < 4; j++)
      if (n + j < N) C[(size_t)(m + i) * N + n + j] = acc[i][j];
}

/* ---------- K3: depthwise causal conv (4 taps) + silu -> xc ------------- */
__global__ void k_conv(const float* __restrict__ zx, const float* __restrict__ cw,
                       const float* __restrict__ cb, float* __restrict__ xc) {
  int tid = blockIdx.x * blockDim.x + threadIdx.x;
  if (tid >= ROWS * CONV_DIM) return;
  int c   = tid % CONV_DIM;
  int row = tid / CONV_DIM;
  int b = row / SEQLEN, l = row % SEQLEN;
  float acc = cb[c];
#pragma unroll
  for (int k = 0; k < D_CONV; k++) {
    int t = l + k - (D_CONV - 1);
    if (t >= 0)
      acc += zx[(size_t)(b * SEQLEN + t) * D_IN_PROJ + D_INNER + c] * cw[c * D_CONV + k];
  }
  xc[tid] = acc / (1.f + expf(-acc));   /* silu */
}

/* ------- K4a: per-chunk dt/cumsum + chunk state S (48x64 per chunk) ----- */
/* grid = B*H*NCHK blocks x 256 threads.                                    */
__global__ __launch_bounds__(256) void k_chunk1(const float* __restrict__ zx,
                                                const float* __restrict__ xc,
                                                const float* __restrict__ dt_bias,
                                                const float* __restrict__ A_log,
                                                float* __restrict__ dtv,
                                                float* __restrict__ cav,
                                                float* __restrict__ Schunk) {
  __shared__ __align__(16) float B_lds[Q][68];
  __shared__ __align__(16) float xw_lds[Q][52];
  __shared__ float s0[Q], s1[Q], dt_l[Q];
  int blk = blockIdx.x;
  int c  = blk & (NCHK - 1);
  int bh = blk / NCHK;
  int h = bh & (NHEADS - 1), b = bh >> 3;
  int tid = threadIdx.x;
  float Aneg = -expf(A_log[h]);
  float dtb  = dt_bias[h];
  size_t rowbase = (size_t)b * SEQLEN + (size_t)c * Q;

  /* phase 1: dt softplus + inclusive cumsum of a = dt*A */
  if (tid < Q) {
    float draw = zx[(rowbase + tid) * D_IN_PROJ + (D_INNER + CONV_DIM) + h] + dtb;
    float dts = draw > 20.f ? draw : log1pf(expf(draw));
    dt_l[tid] = dts;
    s0[tid] = dts * Aneg;
  }
  __syncthreads();
  float* src = s0; float* dst = s1;
  for (int off = 1; off < Q; off <<= 1) {
    if (tid < Q) dst[tid] = src[tid] + (tid >= off ? src[tid - off] : 0.f);
    __syncthreads();
    float* tsw = src; src = dst; dst = tsw;
  }
  size_t cbase = (size_t)bh * SEQLEN + (size_t)c * Q;
  if (tid < Q) { cav[cbase + tid] = src[tid]; dtv[cbase + tid] = dt_l[tid]; }
  float cAend = src[Q - 1];

  /* phase 2: stage B chunk and weighted x into LDS */
#pragma unroll
  for (int k = 0; k < 8; k++) {
    int idx4 = tid + k * 256;               /* 2048 float4s */
    int s = idx4 >> 4, nq = idx4 & 15;
    float4 v = *(const float4*)&xc[(rowbase + s) * CONV_DIM + D_INNER + nq * 4];
    *(float4*)&B_lds[s][nq * 4] = v;
  }
  {
    int s = tid >> 1, poff = (tid & 1) * 24;
    float wgt = expf(cAend - src[s]) * dt_l[s];
    const float* xp = &xc[(rowbase + s) * CONV_DIM + h * HEADDIM + poff];
#pragma unroll
    for (int k = 0; k < 6; k++) {
      float4 v = *(const float4*)&xp[k * 4];
      xw_lds[s][poff + k * 4 + 0] = wgt * v.x;
      xw_lds[s][poff + k * 4 + 1] = wgt * v.y;
      xw_lds[s][poff + k * 4 + 2] = wgt * v.z;
      xw_lds[s][poff + k * 4 + 3] = wgt * v.w;
    }
  }
  __syncthreads();

  /* phase 3: S[p][n] = sum_s xw[s][p] * B[s][n]; wave owns 12 p's */
  int n = tid & 63, p0 = tid >> 6;
  float S[12];
#pragma unroll
  for (int j = 0; j < 12; j++) S[j] = 0.f;
  for (int s = 0; s < Q; s++) {
    float bw = B_lds[s][n];
    float4 x0 = *(const float4*)&xw_lds[s][p0 * 12 + 0];
    float4 x1 = *(const float4*)&xw_lds[s][p0 * 12 + 4];
    float4 x2 = *(const float4*)&xw_lds[s][p0 * 12 + 8];
    S[0] = fmaf(x0.x, bw, S[0]); S[1]  = fmaf(x0.y, bw, S[1]);
    S[2] = fmaf(x0.z, bw, S[2]); S[3]  = fmaf(x0.w, bw, S[3]);
    S[4] = fmaf(x1.x, bw, S[4]); S[5]  = fmaf(x1.y, bw, S[5]);
    S[6] = fmaf(x1.z, bw, S[6]); S[7]  = fmaf(x1.w, bw, S[7]);
    S[8] = fmaf(x2.x, bw, S[8]); S[9]  = fmaf(x2.y, bw, S[9]);
    S[10]= fmaf(x2.z, bw, S[10]);S[11] = fmaf(x2.w, bw, S[11]);
  }
  float* Sout = Schunk + (size_t)(bh * NCHK + c) * SSIZE;
#pragma unroll
  for (int j = 0; j < 12; j++) Sout[(p0 * 12 + j) * 64 + n] = S[j];
}

/* --------- K4b: inter-chunk state recurrence (32 serial steps) ---------- */
/* grid = B*H*12 blocks x 256 threads; each thread owns one (p,n) element.  */
__global__ __launch_bounds__(256) void k_chunk2(const float* __restrict__ cav,
                                                const float* __restrict__ Schunk,
                                                float* __restrict__ Sprev) {
  __shared__ float dec[NCHK];
  int bh = blockIdx.x / 12, seg = blockIdx.x % 12;
  int tid = threadIdx.x;
  if (tid < NCHK) dec[tid] = expf(cav[(size_t)bh * SEQLEN + tid * Q + Q - 1]);
  __syncthreads();
  int e = seg * 256 + tid;
  size_t base = (size_t)bh * NCHK * SSIZE + e;
  float run = 0.f;
  for (int c = 0; c < NCHK; c++) {
    size_t idx = base + (size_t)c * SSIZE;
    Sprev[idx] = run;
    run = fmaf(run, dec[c], Schunk[idx]);
  }
}

/* ------ K4c: intra-chunk output: causal score GEMM + PV + state inj ----- */
/* grid = B*H*NCHK blocks x 256 threads (4 waves). ~78KB LDS, 2 blocks/CU.  */
__global__ __launch_bounds__(256) void k_chunk3(const float* __restrict__ xc,
                                                const float* __restrict__ dtv,
                                                const float* __restrict__ cav,
                                                const float* __restrict__ Sprev,
                                                const float* __restrict__ Dp,
                                                float* __restrict__ y) {
  __shared__ __align__(16) float C_lds[Q][68];
  __shared__ __align__(16) float Bt[32][68];
  __shared__ float xt[32][49];
  __shared__ float SpT[64][49];
  __shared__ float P_l[4][32][33];
  __shared__ float ca_l[Q], dt_l2[Q];
  int blk = blockIdx.x;
  int c  = blk & (NCHK - 1);
  int bh = blk / NCHK;
  int h = bh & (NHEADS - 1), b = bh >> 3;
  int tid = threadIdx.x, w = tid >> 6, lane = tid & 63;
  int tb = lane >> 3, pb = lane & 7;
  size_t rowbase = (size_t)b * SEQLEN + (size_t)c * Q;
  size_t cbase   = (size_t)bh * SEQLEN + (size_t)c * Q;
  float Dh = Dp[h];

  /* stage C chunk (float4), ca/dt, transposed Sprev */
#pragma unroll
  for (int k = 0; k < 8; k++) {
    int idx4 = tid + k * 256;
    int t = idx4 >> 4, nq = idx4 & 15;
    *(float4*)&C_lds[t][nq * 4] =
        *(const float4*)&xc[(rowbase + t) * CONV_DIM + D_INNER + D_STATE + nq * 4];
  }
  if (tid < Q) { ca_l[tid] = cav[cbase + tid]; dt_l2[tid] = dtv[cbase + tid]; }
  {
    const float* Sp = Sprev + (size_t)(bh * NCHK + c) * SSIZE;
#pragma unroll
    for (int k = 0; k < 12; k++) {
      int idx = tid + k * 256;
      int p = idx >> 6, n = idx & 63;
      SpT[n][p] = Sp[idx];
    }
  }
  __syncthreads();

  /* acc = Yinit: exp(cA_t) * C_t . Sprev */
  float acc[4][6];
  {
    float a2[4][6] = {};
    for (int n = 0; n < 64; n++) {
      float cv[4], sv[6];
#pragma unroll
      for (int i = 0; i < 4; i++) cv[i] = C_lds[w * 32 + tb + 8 * i][n];
#pragma unroll
      for (int j = 0; j < 6; j++) sv[j] = SpT[n][pb + 8 * j];
#pragma unroll
      for (int i = 0; i < 4; i++)
#pragma unroll
        for (int j = 0; j < 6; j++) a2[i][j] = fmaf(cv[i], sv[j], a2[i][j]);
    }
#pragma unroll
    for (int i = 0; i < 4; i++) {
      float et = expf(ca_l[w * 32 + tb + 8 * i]);
#pragma unroll
      for (int j = 0; j < 6; j++) acc[i][j] = a2[i][j] * et;
    }
  }

  /* s-tiles: score GEMM -> weight -> PV GEMM */
  for (int st = 0; st < 4; st++) {
    __syncthreads();
#pragma unroll
    for (int k = 0; k < 2; k++) {
      int idx4 = tid + k * 256;
      int s = idx4 >> 4, nq = idx4 & 15;
      *(float4*)&Bt[s][nq * 4] =
          *(const float4*)&xc[(rowbase + st * 32 + s) * CONV_DIM + D_INNER + nq * 4];
    }
    {
      int s = tid >> 3, poff = (tid & 7) * 6;
      const float* xp = &xc[(rowbase + st * 32 + s) * CONV_DIM + h * HEADDIM + poff];
#pragma unroll
      for (int k = 0; k < 6; k++) xt[s][poff + k] = xp[k];
    }
    __syncthreads();

    float G[4][4] = {};
    for (int n4 = 0; n4 < 64; n4 += 4) {
      float4 Cv[4], Bv[4];
#pragma unroll
      for (int i = 0; i < 4; i++) Cv[i] = *(const float4*)&C_lds[w * 32 + tb + 8 * i][n4];
#pragma unroll
      for (int j = 0; j < 4; j++) Bv[j] = *(const float4*)&Bt[pb + 8 * j][n4];
#pragma unroll
      for (int i = 0; i < 4; i++)
#pragma unroll
        for (int j = 0; j < 4; j++) {
          G[i][j] = fmaf(Cv[i].x, Bv[j].x, G[i][j]);
          G[i][j] = fmaf(Cv[i].y, Bv[j].y, G[i][j]);
          G[i][j] = fmaf(Cv[i].z, Bv[j].z, G[i][j]);
          G[i][j] = fmaf(Cv[i].w, Bv[j].w, G[i][j]);
        }
    }
#pragma unroll
    for (int i = 0; i < 4; i++) {
      int t_loc = tb + 8 * i;
      int t_g = w * 32 + t_loc;
      float cat = ca_l[t_g];
#pragma unroll
      for (int j = 0; j < 4; j++) {
        int s_loc = pb + 8 * j;
        int s_g = st * 32 + s_loc;
        float v = 0.f;
        if (s_g <= t_g) v = G[i][j] * expf(cat - ca_l[s_g]) * dt_l2[s_g];
        P_l[w][t_loc][s_loc] = v;
      }
    }
    /* per-wave private P tile: same-wave write->read, HW lgkmcnt orders it */
    for (int s = 0; s < 32; s++) {
      float pv[4], xv[6];
#pragma unroll
      for (int i = 0; i < 4; i++) pv[i] = P_l[w][tb + 8 * i][s];
#pragma unroll
      for (int j = 0; j < 6; j++) xv[j] = xt[s][pb + 8 * j];
#pragma unroll
      for (int i = 0; i < 4; i++)
#pragma unroll
        for (int j = 0; j < 6; j++) acc[i][j] = fmaf(pv[i], xv[j], acc[i][j]);
    }
    if (st == w) {   /* D*x_t for own rows (wave-uniform branch) */
#pragma unroll
      for (int i = 0; i < 4; i++)
#pragma unroll
        for (int j = 0; j < 6; j++)
          acc[i][j] = fmaf(Dh, xt[tb + 8 * i][pb + 8 * j], acc[i][j]);
    }
  }

  float* yb = y + rowbase * D_INNER + h * HEADDIM;
#pragma unroll
  for (int i = 0; i < 4; i++)
#pragma unroll
    for (int j = 0; j < 6; j++)
      yb[(size_t)(w * 32 + tb + 8 * i) * D_INNER + pb + 8 * j] = acc[i][j];
}

/* ---------- K5a: gate with silu(z), RMSNorm ----------------------------- */
__global__ __launch_bounds__(128) void k_gate_rms(const float* __restrict__ y,
                                                  const float* __restrict__ zx,
                                                  const float* __restrict__ nw,
                                                  float* __restrict__ ynorm) {
  int row = blockIdx.x;
  int tid = threadIdx.x;
  float v[3];
  float ssq = 0.f;
#pragma unroll
  for (int j = 0; j < 3; j++) {
    int e = tid + j * 128;
    float s = y[(size_t)row * D_INNER + e];
    float zr = zx[(size_t)row * D_IN_PROJ + e];
    s *= zr / (1.f + expf(-zr));
    v[j] = s;
    ssq += s * s;
  }
#pragma unroll
  for (int o = 32; o > 0; o >>= 1) ssq += __shfl_down(ssq, o);
  __shared__ float red[2];
  if ((tid & 63) == 0) red[tid >> 6] = ssq;
  __syncthreads();
  float inv = rsqrtf((red[0] + red[1]) * (1.f / D_INNER) + 1e-5f);
#pragma unroll
  for (int j = 0; j < 3; j++) {
    int e = tid + j * 128;
    ynorm[(size_t)row * D_INNER + e] = v[j] * inv * nw[e];
  }
}

/* -------------- K5c: residual add + LayerNorm (in place on z) ----------- */
__global__ __launch_bounds__(64) void k_res_ln(const float* __restrict__ tin,
                                               float* zio,
                                               const float* __restrict__ lnw,
                                               const float* __restrict__ lnb) {
  int row = blockIdx.x;
  int tid = threadIdx.x;
  size_t base = (size_t)row * D_MODEL;
  float v0 = tin[base + tid]       + zio[base + tid];
  float v1 = tin[base + tid + 64]  + zio[base + tid + 64];
  float v2 = tin[base + tid + 128] + zio[base + tid + 128];
  float s = v0 + v1 + v2;
#pragma unroll
  for (int o = 32; o > 0; o >>= 1) s += __shfl_down(s, o);
  float mu = __shfl(s, 0) * (1.f / D_MODEL);
  float d0 = v0 - mu, d1 = v1 - mu, d2 = v2 - mu;
  float q = d0 * d0 + d1 * d1 + d2 * d2;
#pragma unroll
  for (int o = 32; o > 0; o >>= 1) q += __shfl_down(q, o);
  float inv = rsqrtf(__shfl(q, 0) * (1.f / D_MODEL) + 1e-5f);
  zio[base + tid]       = d0 * inv * lnw[tid]       + lnb[tid];
  zio[base + tid + 64]  = d1 * inv * lnw[tid + 64]  + lnb[tid + 64];
  zio[base + tid + 128] = d2 * inv * lnw[tid + 128] + lnb[tid + 128];
}

/* ------------- K6: output linear + transpose to (B, 4, L) --------------- */
__global__ void k_lin_out(const float* __restrict__ z, const float* __restrict__ w,
                          const float* __restrict__ bias, float* __restrict__ out) {
  int tid = blockIdx.x * blockDim.x + threadIdx.x;
  if (tid >= ROWS) return;
  int b = tid / SEQLEN, l = tid % SEQLEN;
  float acc0 = bias[0], acc1 = bias[1], acc2 = bias[2], acc3 = bias[3];
  const float* zr = z + (size_t)tid * D_MODEL;
  for (int d = 0; d < D_MODEL; d += 4) {
    float4 zv = *(const float4*)&zr[d];
    acc0 = fmaf(zv.x, w[0 * D_MODEL + d], acc0); acc0 = fmaf(zv.y, w[0 * D_MODEL + d + 1], acc0);
    acc0 = fmaf(zv.z, w[0 * D_MODEL + d + 2], acc0); acc0 = fmaf(zv.w, w[0 * D_MODEL + d + 3], acc0);
    acc1 = fmaf(zv.x, w[1 * D_MODEL + d], acc1); acc1 = fmaf(zv.y, w[1 * D_MODEL + d + 1], acc1);
    acc1 = fmaf(zv.z, w[1 * D_MODEL + d + 2], acc1); acc1 = fmaf(zv.w, w[1 * D_MODEL + d + 3], acc1);
    acc2 = fmaf(zv.x, w[2 * D_MODEL + d], acc2); acc2 = fmaf(zv.y, w[2 * D_MODEL + d + 1], acc2);
    acc2 = fmaf(zv.z, w[2 * D_MODEL + d + 2], acc2); acc2 = fmaf(zv.w, w[2 * D_MODEL + d + 3], acc2);
    acc3 = fmaf(zv.x, w[3 * D_MODEL + d], acc3); acc3 = fmaf(zv.y, w[3 * D_MODEL + d + 1], acc3);
    acc3 = fmaf(zv.z, w[3 * D_MODEL + d + 2], acc3); acc3 = fmaf(zv.w, w[3 * D_MODEL + d + 3], acc3);
  }
  out[((size_t)b * OUTPUT_DIM + 0) * SEQLEN + l] = acc0;
  out[((size_t)b * OUTPUT_DIM + 1) * SEQLEN + l] = acc1;
  out[((size_t)b * OUTPUT_DIM + 2) * SEQLEN + l] = acc2;
  out[((size_t)b * OUTPUT_DIM + 3) * SEQLEN + l] = acc3;
}

/* ------------------------------- launch --------------------------------- */
extern "C" void kernel_launch(void* const* d_in, const int* in_sizes, int n_in,
                              void* d_out, int out_size, void* d_ws, size_t ws_size,
                              hipStream_t stream) {
  const float* inp       = (const float*)d_in[0];
  const float* lin_in_w  = (const float*)d_in[1];
  const float* lin_in_b  = (const float*)d_in[2];
  const float* in_w      = (const float*)d_in[3];
  const float* conv_w    = (const float*)d_in[4];
  const float* conv_b    = (const float*)d_in[5];
  const float* dt_bias   = (const float*)d_in[6];
  const float* A_log     = (const float*)d_in[7];
  const float* Dmat      = (const float*)d_in[8];
  const float* norm_w    = (const float*)d_in[9];
  const float* out_w     = (const float*)d_in[10];
  const float* ln_w      = (const float*)d_in[11];
  const float* ln_b      = (const float*)d_in[12];
  const float* lin_out_w = (const float*)d_in[13];
  const float* lin_out_b = (const float*)d_in[14];
  float* out = (float*)d_out;

  float* ws = (float*)d_ws;
  size_t off = 0;
  float* z      = ws + off; off += (size_t)ROWS * D_MODEL;
  float* zx     = ws + off; off += (size_t)ROWS * D_IN_PROJ;
  float* xc     = ws + off; off += (size_t)ROWS * CONV_DIM;
  float* y      = ws + off; off += (size_t)ROWS * D_INNER;
  float* ynorm  = ws + off; off += (size_t)ROWS * D_INNER;
  float* tmp    = ws + off; off += (size_t)ROWS * D_MODEL;
  float* dtv    = ws + off; off += (size_t)BATCH * NHEADS * SEQLEN;
  float* cav    = ws + off; off += (size_t)BATCH * NHEADS * SEQLEN;
  float* Schunk = ws + off; off += (size_t)BATCH * NHEADS * NCHK * SSIZE;
  float* Sprev  = ws + off; off += (size_t)BATCH * NHEADS * NCHK * SSIZE;

  k_lin_in<<<(ROWS * D_MODEL + 255) / 256, 256, 0, stream>>>(inp, lin_in_w, lin_in_b, z);

  for (int i = 0; i < NLAYERS; i++) {
    k_gemm_abt<<<dim3(ROWS / 64, (D_IN_PROJ + 63) / 64), 256, 0, stream>>>(
        z, in_w + (size_t)i * D_IN_PROJ * D_MODEL, zx, ROWS, D_IN_PROJ, D_MODEL);
    k_conv<<<(ROWS * CONV_DIM + 255) / 256, 256, 0, stream>>>(
        zx, conv_w + (size_t)i * CONV_DIM * D_CONV, conv_b + (size_t)i * CONV_DIM, xc);
    k_chunk1<<<BATCH * NHEADS * NCHK, 256, 0, stream>>>(
        zx, xc, dt_bias + i * NHEADS, A_log + i * NHEADS, dtv, cav, Schunk);
    k_chunk2<<<BATCH * NHEADS * 12, 256, 0, stream>>>(cav, Schunk, Sprev);
    k_chunk3<<<BATCH * NHEADS * NCHK, 256, 0, stream>>>(
        xc, dtv, cav, Sprev, Dmat + i * NHEADS, y);
    k_gate_rms<<<ROWS, 128, 0, stream>>>(y, zx, norm_w + (size_t)i * D_INNER, ynorm);
    k_gemm_abt<<<dim3(ROWS / 64, (D_MODEL + 63) / 64), 256, 0, stream>>>(
        ynorm, out_w + (size_t)i * D_MODEL * D_INNER, tmp, ROWS, D_MODEL, D_INNER);
    k_res_ln<<<ROWS, 64, 0, stream>>>(tmp, z, ln_w + (size_t)i * D_MODEL, ln_b + (size_t)i * D_MODEL);
  }

  k_lin_out<<<(ROWS + 255) / 256, 256, 0, stream>>>(z, lin_out_w, lin_out_b, out);
}

// Round 11
// 1587.688 us; speedup vs baseline: 12.8075x; 3.1812x over previous
//
#include <hip/hip_runtime.h>
#include <math.h>

#define BATCH    4
#define SEQLEN   4096
#define INPUT_DIM 3
#define OUTPUT_DIM 4
#define D_MODEL  192
#define D_INNER  384
#define NHEADS   8
#define HEADDIM  48
#define D_STATE  64
#define CONV_DIM 512        /* D_INNER + 2*D_STATE */
#define D_IN_PROJ 904       /* 2*D_INNER + 2*D_STATE + NHEADS */
#define D_CONV   4
#define NLAYERS  8
#define ROWS     (BATCH*SEQLEN)   /* 16384 */

#define Q     128                 /* scan chunk length */
#define NCHK  (SEQLEN/Q)          /* 32 chunks */
#define SSIZE (HEADDIM*D_STATE)   /* 3072 per-chunk state */

/* ------------- bf16 split helpers (RNE hi/lo, 4-term MFMA) -------------- */
typedef __bf16 bf16x8 __attribute__((ext_vector_type(8)));
typedef short  s16x8  __attribute__((ext_vector_type(8)));
typedef float  f32x4  __attribute__((ext_vector_type(4)));

/* round-to-nearest-even bf16 (not truncation: halves residual, kills bias) */
__device__ __forceinline__ unsigned short bf_rne(float x) {
  union { float f; unsigned u; } v; v.f = x;
  unsigned r = v.u + 0x7FFFu + ((v.u >> 16) & 1u);
  return (unsigned short)(r >> 16);
}
__device__ __forceinline__ float bf_f(unsigned short h) {
  union { float f; unsigned u; } v; v.u = ((unsigned)h) << 16; return v.f;
}
__device__ __forceinline__ void split2(float x, unsigned short& h, unsigned short& l) {
  h = bf_rne(x);
  l = bf_rne(x - bf_f(h));
}
/* load 8 contiguous fp32 from global, split into bf16 hi + lo vectors */
__device__ __forceinline__ void ldcvt8(const float* __restrict__ g, s16x8& hi, s16x8& lo) {
  float t[8];
  *(float4*)&t[0] = *(const float4*)g;
  *(float4*)&t[4] = *(const float4*)(g + 4);
#pragma unroll
  for (int i = 0; i < 8; i++) {
    unsigned short h, l;
    split2(t[i], h, l);
    hi[i] = (short)h;
    lo[i] = (short)l;
  }
}
/* full 4-term product: (ah+al)(bh+bl) */
__device__ __forceinline__ void mfma4(f32x4& acc, s16x8 ah, s16x8 al, s16x8 bh, s16x8 bl) {
  acc = __builtin_amdgcn_mfma_f32_16x16x32_bf16(
      __builtin_bit_cast(bf16x8, ah), __builtin_bit_cast(bf16x8, bh), acc, 0, 0, 0);
  acc = __builtin_amdgcn_mfma_f32_16x16x32_bf16(
      __builtin_bit_cast(bf16x8, ah), __builtin_bit_cast(bf16x8, bl), acc, 0, 0, 0);
  acc = __builtin_amdgcn_mfma_f32_16x16x32_bf16(
      __builtin_bit_cast(bf16x8, al), __builtin_bit_cast(bf16x8, bh), acc, 0, 0, 0);
  acc = __builtin_amdgcn_mfma_f32_16x16x32_bf16(
      __builtin_bit_cast(bf16x8, al), __builtin_bit_cast(bf16x8, bl), acc, 0, 0, 0);
}

/* ------------- K0: split fp32 array into bf16 hi/lo (weights) ----------- */
__global__ void k_cvt(const float* __restrict__ in, unsigned short* __restrict__ h,
                      unsigned short* __restrict__ l, int n) {
  int i = blockIdx.x * blockDim.x + threadIdx.x;
  if (i >= n) return;
  unsigned short hh, ll;
  split2(in[i], hh, ll);
  h[i] = hh; l[i] = ll;
}

/* ------- K1: input linear + relu -> z (fp32) + zh/zl (bf16 split) ------- */
__global__ void k_lin_in(const float* __restrict__ inp, const float* __restrict__ w,
                         const float* __restrict__ b, float* __restrict__ z,
                         unsigned short* __restrict__ zh, unsigned short* __restrict__ zl) {
  int tid = blockIdx.x * blockDim.x + threadIdx.x;
  if (tid >= ROWS * D_MODEL) return;
  int d   = tid % D_MODEL;
  int row = tid / D_MODEL;
  int bb  = row / SEQLEN, l = row % SEQLEN;
  float acc = b[d];
#pragma unroll
  for (int i = 0; i < INPUT_DIM; i++)
    acc += inp[(size_t)(bb * INPUT_DIM + i) * SEQLEN + l] * w[d * INPUT_DIM + i];
  float v = fmaxf(acc, 0.f);
  z[tid] = v;
  unsigned short hh, ll;
  split2(v, hh, ll);
  zh[tid] = hh; zl[tid] = ll;
}

/* ----- K2 (MFMA): C[M][N] = A[M][K] @ B[N][K]^T, pre-split bf16 hi/lo ---- */
/* 128x64 tile, BK=32, 4 waves; each wave owns 32 rows x 64 cols.           */
__global__ __launch_bounds__(256) void k_gemm_mfma(const unsigned short* __restrict__ Ah,
                                                   const unsigned short* __restrict__ Al,
                                                   const unsigned short* __restrict__ Bh,
                                                   const unsigned short* __restrict__ Bl,
                                                   float* __restrict__ C,
                                                   int M, int N, int K) {
  __shared__ __align__(16) unsigned short Ash[128][40], Asl[128][40];
  __shared__ __align__(16) unsigned short Bsh[64][40],  Bsl[64][40];
  int tid = threadIdx.x;
  int m0 = blockIdx.x * 128, n0 = blockIdx.y * 64;
  int w = tid >> 6, lane = tid & 63, lr = lane & 15, lq = lane >> 4;
  int ar = tid >> 1, ak = (tid & 1) * 16;   /* A: 2 threads per row */
  int br = tid >> 2, bk = (tid & 3) * 8;    /* B: 4 threads per row */
  f32x4 acc[2][4];
#pragma unroll
  for (int i = 0; i < 2; i++)
#pragma unroll
    for (int j = 0; j < 4; j++) acc[i][j] = (f32x4){0.f, 0.f, 0.f, 0.f};

  for (int kt = 0; kt < K; kt += 32) {
    size_t abase = (size_t)(m0 + ar) * K + kt + ak;
    *(s16x8*)&Ash[ar][ak]     = *(const s16x8*)&Ah[abase];
    *(s16x8*)&Ash[ar][ak + 8] = *(const s16x8*)&Ah[abase + 8];
    *(s16x8*)&Asl[ar][ak]     = *(const s16x8*)&Al[abase];
    *(s16x8*)&Asl[ar][ak + 8] = *(const s16x8*)&Al[abase + 8];
    if (n0 + br < N) {
      size_t bbase = (size_t)(n0 + br) * K + kt + bk;
      *(s16x8*)&Bsh[br][bk] = *(const s16x8*)&Bh[bbase];
      *(s16x8*)&Bsl[br][bk] = *(const s16x8*)&Bl[bbase];
    } else {
      s16x8 zz = {0, 0, 0, 0, 0, 0, 0, 0};
      *(s16x8*)&Bsh[br][bk] = zz;
      *(s16x8*)&Bsl[br][bk] = zz;
    }
    __syncthreads();
    s16x8 a_h[2], a_l[2];
#pragma unroll
    for (int mi = 0; mi < 2; mi++) {
      a_h[mi] = *(const s16x8*)&Ash[w * 32 + mi * 16 + lr][lq * 8];
      a_l[mi] = *(const s16x8*)&Asl[w * 32 + mi * 16 + lr][lq * 8];
    }
#pragma unroll
    for (int nj = 0; nj < 4; nj++) {
      s16x8 b_h = *(const s16x8*)&Bsh[nj * 16 + lr][lq * 8];
      s16x8 b_l = *(const s16x8*)&Bsl[nj * 16 + lr][lq * 8];
#pragma unroll
      for (int mi = 0; mi < 2; mi++)
        mfma4(acc[mi][nj], a_h[mi], a_l[mi], b_h, b_l);
    }
    __syncthreads();
  }
  /* D layout: col=lane&15, row=4*(lane>>4)+reg */
#pragma unroll
  for (int mi = 0; mi < 2; mi++) {
    int m = m0 + w * 32 + mi * 16 + lq * 4;
#pragma unroll
    for (int nj = 0; nj < 4; nj++) {
      int n = n0 + nj * 16 + lr;
      if (n < N) {
#pragma unroll
        for (int r = 0; r < 4; r++)
          C[(size_t)(m + r) * N + n] = acc[mi][nj][r];
      }
    }
  }
}

/* ---------- K3: depthwise causal conv (4 taps) + silu -> xc ------------- */
__global__ void k_conv(const float* __restrict__ zx, const float* __restrict__ cw,
                       const float* __restrict__ cb, float* __restrict__ xc) {
  int tid = blockIdx.x * blockDim.x + threadIdx.x;
  if (tid >= ROWS * CONV_DIM) return;
  int c   = tid % CONV_DIM;
  int row = tid / CONV_DIM;
  int b = row / SEQLEN, l = row % SEQLEN;
  float acc = cb[c];
#pragma unroll
  for (int k = 0; k < D_CONV; k++) {
    int t = l + k - (D_CONV - 1);
    if (t >= 0)
      acc += zx[(size_t)(b * SEQLEN + t) * D_IN_PROJ + D_INNER + c] * cw[c * D_CONV + k];
  }
  xc[tid] = acc / (1.f + expf(-acc));   /* silu */
}

/* ------- K4a: per-chunk dt/cumsum + chunk state S (48x64 per chunk) ----- */
/* dt computed in EXACT fp32 from z . in_w_dt_row (error here is exp-amplified
   through cumsum; bf16-GEMM dt column is ignored). */
__global__ __launch_bounds__(256) void k_chunk1(const float* __restrict__ z,
                                                const float* __restrict__ in_w_l,
                                                const float* __restrict__ xc,
                                                const float* __restrict__ dt_bias,
                                                const float* __restrict__ A_log,
                                                float* __restrict__ dtv,
                                                float* __restrict__ cav,
                                                float* __restrict__ Schunk) {
  __shared__ __align__(16) float B_lds[Q][68];
  __shared__ __align__(16) float xw_lds[Q][52];
  __shared__ float s0[Q], s1[Q], dt_l[Q];
  int blk = blockIdx.x;
  int c  = blk & (NCHK - 1);
  int bh = blk / NCHK;
  int h = bh & (NHEADS - 1), b = bh >> 3;
  int tid = threadIdx.x;
  float Aneg = -expf(A_log[h]);
  float dtb  = dt_bias[h];
  size_t rowbase = (size_t)b * SEQLEN + (size_t)c * Q;

  if (tid < Q) {
    const float* zrow = &z[(rowbase + tid) * D_MODEL];
    const float* wdt  = &in_w_l[(size_t)(D_INNER + CONV_DIM + h) * D_MODEL];
    float draw = dtb;
#pragma unroll
    for (int d = 0; d < D_MODEL; d += 4) {
      float4 zv = *(const float4*)&zrow[d];
      float4 wv = *(const float4*)&wdt[d];
      draw = fmaf(zv.x, wv.x, draw); draw = fmaf(zv.y, wv.y, draw);
      draw = fmaf(zv.z, wv.z, draw); draw = fmaf(zv.w, wv.w, draw);
    }
    float dts = draw > 20.f ? draw : log1pf(expf(draw));
    dt_l[tid] = dts;
    s0[tid] = dts * Aneg;
  }
  __syncthreads();
  float* src = s0; float* dst = s1;
  for (int off = 1; off < Q; off <<= 1) {
    if (tid < Q) dst[tid] = src[tid] + (tid >= off ? src[tid - off] : 0.f);
    __syncthreads();
    float* tsw = src; src = dst; dst = tsw;
  }
  size_t cbase = (size_t)bh * SEQLEN + (size_t)c * Q;
  if (tid < Q) { cav[cbase + tid] = src[tid]; dtv[cbase + tid] = dt_l[tid]; }
  float cAend = src[Q - 1];

#pragma unroll
  for (int k = 0; k < 8; k++) {
    int idx4 = tid + k * 256;
    int s = idx4 >> 4, nq = idx4 & 15;
    float4 v = *(const float4*)&xc[(rowbase + s) * CONV_DIM + D_INNER + nq * 4];
    *(float4*)&B_lds[s][nq * 4] = v;
  }
  {
    int s = tid >> 1, poff = (tid & 1) * 24;
    float wgt = expf(cAend - src[s]) * dt_l[s];
    const float* xp = &xc[(rowbase + s) * CONV_DIM + h * HEADDIM + poff];
#pragma unroll
    for (int k = 0; k < 6; k++) {
      float4 v = *(const float4*)&xp[k * 4];
      xw_lds[s][poff + k * 4 + 0] = wgt * v.x;
      xw_lds[s][poff + k * 4 + 1] = wgt * v.y;
      xw_lds[s][poff + k * 4 + 2] = wgt * v.z;
      xw_lds[s][poff + k * 4 + 3] = wgt * v.w;
    }
  }
  __syncthreads();

  int n = tid & 63, p0 = tid >> 6;
  float S[12];
#pragma unroll
  for (int j = 0; j < 12; j++) S[j] = 0.f;
  for (int s = 0; s < Q; s++) {
    float bw = B_lds[s][n];
    float4 x0 = *(const float4*)&xw_lds[s][p0 * 12 + 0];
    float4 x1 = *(const float4*)&xw_lds[s][p0 * 12 + 4];
    float4 x2 = *(const float4*)&xw_lds[s][p0 * 12 + 8];
    S[0] = fmaf(x0.x, bw, S[0]); S[1]  = fmaf(x0.y, bw, S[1]);
    S[2] = fmaf(x0.z, bw, S[2]); S[3]  = fmaf(x0.w, bw, S[3]);
    S[4] = fmaf(x1.x, bw, S[4]); S[5]  = fmaf(x1.y, bw, S[5]);
    S[6] = fmaf(x1.z, bw, S[6]); S[7]  = fmaf(x1.w, bw, S[7]);
    S[8] = fmaf(x2.x, bw, S[8]); S[9]  = fmaf(x2.y, bw, S[9]);
    S[10]= fmaf(x2.z, bw, S[10]);S[11] = fmaf(x2.w, bw, S[11]);
  }
  float* Sout = Schunk + (size_t)(bh * NCHK + c) * SSIZE;
#pragma unroll
  for (int j = 0; j < 12; j++) Sout[(p0 * 12 + j) * 64 + n] = S[j];
}

/* --------- K4b: inter-chunk state recurrence (32 serial steps) ---------- */
__global__ __launch_bounds__(256) void k_chunk2(const float* __restrict__ cav,
                                                const float* __restrict__ Schunk,
                                                float* __restrict__ Sprev) {
  __shared__ float dec[NCHK];
  int bh = blockIdx.x / 12, seg = blockIdx.x % 12;
  int tid = threadIdx.x;
  if (tid < NCHK) dec[tid] = expf(cav[(size_t)bh * SEQLEN + tid * Q + Q - 1]);
  __syncthreads();
  int e = seg * 256 + tid;
  size_t base = (size_t)bh * NCHK * SSIZE + e;
  float run = 0.f;
  for (int c = 0; c < NCHK; c++) {
    size_t idx = base + (size_t)c * SSIZE;
    Sprev[idx] = run;
    run = fmaf(run, dec[c], Schunk[idx]);
  }
}

/* ------ K4c (MFMA): intra-chunk output via bf16-split matrix cores ------ */
#define XT_P 136
#define SP_P 72
#define PP_P 40
__global__ __launch_bounds__(256, 3) void k_chunk3m(const float* __restrict__ xc,
                                                    const float* __restrict__ dtv,
                                                    const float* __restrict__ cav,
                                                    const float* __restrict__ Sprev,
                                                    const float* __restrict__ Dp,
                                                    float* __restrict__ y) {
  __shared__ __align__(16) unsigned short XTh[48][XT_P], XTl[48][XT_P];
  __shared__ __align__(16) unsigned short Sph[48][SP_P], Spl[48][SP_P];
  __shared__ __align__(16) unsigned short Ph[4][16][PP_P], Pl[4][16][PP_P];
  __shared__ float ca_l[Q], dt_l[Q];
  int blk = blockIdx.x;
  int c  = blk & (NCHK - 1);
  int bh = blk / NCHK;
  int h = bh & (NHEADS - 1), b = bh >> 3;
  int tid = threadIdx.x, w = tid >> 6, lane = tid & 63;
  int lr = lane & 15, lq = lane >> 4;
  size_t rowbase = (size_t)b * SEQLEN + (size_t)c * Q;
  size_t cbase   = (size_t)bh * SEQLEN + (size_t)c * Q;
  float Dh = Dp[h];

  if (tid < Q) { ca_l[tid] = cav[cbase + tid]; dt_l[tid] = dtv[cbase + tid]; }
  {
    const float* Sg = Sprev + (size_t)(bh * NCHK + c) * SSIZE;
#pragma unroll
    for (int k = 0; k < 12; k++) {
      int e = tid + k * 256;
      int p = e >> 6, n = e & 63;
      unsigned short hh, ll;
      split2(Sg[e], hh, ll);
      Sph[p][n] = hh; Spl[p][n] = ll;
    }
  }
  {
    int s = tid >> 1, p0 = (tid & 1) * 24;
    const float* xp = &xc[(rowbase + s) * CONV_DIM + h * HEADDIM + p0];
#pragma unroll
    for (int k = 0; k < 24; k += 4) {
      float4 v = *(const float4*)&xp[k];
      float vv[4] = {v.x, v.y, v.z, v.w};
#pragma unroll
      for (int j = 0; j < 4; j++) {
        unsigned short hh, ll;
        split2(vv[j], hh, ll);
        XTh[p0 + k + j][s] = hh;
        XTl[p0 + k + j][s] = ll;
      }
    }
  }
  __syncthreads();

#pragma unroll
  for (int rt = 0; rt < 2; rt++) {
    int r  = rt ? (7 - w) : w;
    int t0 = r << 4;
    s16x8 Ah[2], Al[2];
#pragma unroll
    for (int k2 = 0; k2 < 2; k2++)
      ldcvt8(&xc[(rowbase + t0 + lr) * CONV_DIM + (D_INNER + D_STATE) + k2 * 32 + lq * 8],
             Ah[k2], Al[k2]);

    f32x4 acc[3];
#pragma unroll
    for (int pt = 0; pt < 3; pt++) {
      f32x4 a = {0.f, 0.f, 0.f, 0.f};
#pragma unroll
      for (int k2 = 0; k2 < 2; k2++) {
        s16x8 bh8 = *(const s16x8*)&Sph[pt * 16 + lr][k2 * 32 + lq * 8];
        s16x8 bl8 = *(const s16x8*)&Spl[pt * 16 + lr][k2 * 32 + lq * 8];
        mfma4(a, Ah[k2], Al[k2], bh8, bl8);
      }
      acc[pt] = a;
    }
    float et[4];
#pragma unroll
    for (int rr = 0; rr < 4; rr++) et[rr] = expf(ca_l[t0 + lq * 4 + rr]);
#pragma unroll
    for (int pt = 0; pt < 3; pt++)
#pragma unroll
      for (int rr = 0; rr < 4; rr++) acc[pt][rr] *= et[rr];

    for (int u = 0; u <= (r >> 1); u++) {
#pragma unroll
      for (int v2 = 0; v2 < 2; v2++) {
        int v = 2 * u + v2;
        if (v <= r) {
          f32x4 g = {0.f, 0.f, 0.f, 0.f};
#pragma unroll
          for (int k2 = 0; k2 < 2; k2++) {
            s16x8 bh8, bl8;
            ldcvt8(&xc[(rowbase + v * 16 + lr) * CONV_DIM + D_INNER + k2 * 32 + lq * 8],
                   bh8, bl8);
            mfma4(g, Ah[k2], Al[k2], bh8, bl8);
          }
          int s = v * 16 + lr;
          float cas = ca_l[s], dts = dt_l[s];
#pragma unroll
          for (int rr = 0; rr < 4; rr++) {
            int t = t0 + lq * 4 + rr;
            float pv = (s <= t) ? g[rr] * expf(ca_l[t] - cas) * dts : 0.f;
            unsigned short hh, ll;
            split2(pv, hh, ll);
            Ph[w][lq * 4 + rr][v2 * 16 + lr] = hh;
            Pl[w][lq * 4 + rr][v2 * 16 + lr] = ll;
          }
        } else {
#pragma unroll
          for (int rr = 0; rr < 4; rr++) {
            Ph[w][lq * 4 + rr][v2 * 16 + lr] = 0;
            Pl[w][lq * 4 + rr][v2 * 16 + lr] = 0;
          }
        }
      }
      s16x8 pah = *(const s16x8*)&Ph[w][lr][lq * 8];
      s16x8 pal = *(const s16x8*)&Pl[w][lr][lq * 8];
#pragma unroll
      for (int pt = 0; pt < 3; pt++) {
        s16x8 xbh = *(const s16x8*)&XTh[pt * 16 + lr][u * 32 + lq * 8];
        s16x8 xbl = *(const s16x8*)&XTl[pt * 16 + lr][u * 32 + lq * 8];
        mfma4(acc[pt], pah, pal, xbh, xbl);
      }
    }

#pragma unroll
    for (int pt = 0; pt < 3; pt++)
#pragma unroll
      for (int rr = 0; rr < 4; rr++) {
        int t = t0 + lq * 4 + rr, p = pt * 16 + lr;
        float xv = bf_f(XTh[p][t]) + bf_f(XTl[p][t]);
        y[(rowbase + t) * D_INNER + h * HEADDIM + p] = acc[pt][rr] + Dh * xv;
      }
  }
}

/* ---------- K5a: gate with silu(z), RMSNorm -> bf16 hi/lo output -------- */
__global__ __launch_bounds__(128) void k_gate_rms(const float* __restrict__ y,
                                                  const float* __restrict__ zx,
                                                  const float* __restrict__ nw,
                                                  unsigned short* __restrict__ yh,
                                                  unsigned short* __restrict__ yl) {
  int row = blockIdx.x;
  int tid = threadIdx.x;
  float v[3];
  float ssq = 0.f;
#pragma unroll
  for (int j = 0; j < 3; j++) {
    int e = tid + j * 128;
    float s = y[(size_t)row * D_INNER + e];
    float zr = zx[(size_t)row * D_IN_PROJ + e];
    s *= zr / (1.f + expf(-zr));
    v[j] = s;
    ssq += s * s;
  }
#pragma unroll
  for (int o = 32; o > 0; o >>= 1) ssq += __shfl_down(ssq, o);
  __shared__ float red[2];
  if ((tid & 63) == 0) red[tid >> 6] = ssq;
  __syncthreads();
  float inv = rsqrtf((red[0] + red[1]) * (1.f / D_INNER) + 1e-5f);
#pragma unroll
  for (int j = 0; j < 3; j++) {
    int e = tid + j * 128;
    float o = v[j] * inv * nw[e];
    unsigned short hh, ll;
    split2(o, hh, ll);
    yh[(size_t)row * D_INNER + e] = hh;
    yl[(size_t)row * D_INNER + e] = ll;
  }
}

/* ---- K5c: residual add + LayerNorm (in place on z) + bf16 hi/lo out ---- */
__global__ __launch_bounds__(64) void k_res_ln(const float* __restrict__ tin,
                                               float* zio,
                                               const float* __restrict__ lnw,
                                               const float* __restrict__ lnb,
                                               unsigned short* __restrict__ zh,
                                               unsigned short* __restrict__ zl) {
  int row = blockIdx.x;
  int tid = threadIdx.x;
  size_t base = (size_t)row * D_MODEL;
  float v0 = tin[base + tid]       + zio[base + tid];
  float v1 = tin[base + tid + 64]  + zio[base + tid + 64];
  float v2 = tin[base + tid + 128] + zio[base + tid + 128];
  float s = v0 + v1 + v2;
#pragma unroll
  for (int o = 32; o > 0; o >>= 1) s += __shfl_down(s, o);
  float mu = __shfl(s, 0) * (1.f / D_MODEL);
  float d0 = v0 - mu, d1 = v1 - mu, d2 = v2 - mu;
  float q = d0 * d0 + d1 * d1 + d2 * d2;
#pragma unroll
  for (int o = 32; o > 0; o >>= 1) q += __shfl_down(q, o);
  float inv = rsqrtf(__shfl(q, 0) * (1.f / D_MODEL) + 1e-5f);
  float o0 = d0 * inv * lnw[tid]       + lnb[tid];
  float o1 = d1 * inv * lnw[tid + 64]  + lnb[tid + 64];
  float o2 = d2 * inv * lnw[tid + 128] + lnb[tid + 128];
  zio[base + tid]       = o0;
  zio[base + tid + 64]  = o1;
  zio[base + tid + 128] = o2;
  unsigned short h0, l0, h1, l1, h2, l2;
  split2(o0, h0, l0); split2(o1, h1, l1); split2(o2, h2, l2);
  zh[base + tid]       = h0; zl[base + tid]       = l0;
  zh[base + tid + 64]  = h1; zl[base + tid + 64]  = l1;
  zh[base + tid + 128] = h2; zl[base + tid + 128] = l2;
}

/* ------------- K6: output linear + transpose to (B, 4, L) --------------- */
__global__ void k_lin_out(const float* __restrict__ z, const float* __restrict__ w,
                          const float* __restrict__ bias, float* __restrict__ out) {
  int tid = blockIdx.x * blockDim.x + threadIdx.x;
  if (tid >= ROWS) return;
  int b = tid / SEQLEN, l = tid % SEQLEN;
  float acc0 = bias[0], acc1 = bias[1], acc2 = bias[2], acc3 = bias[3];
  const float* zr = z + (size_t)tid * D_MODEL;
  for (int d = 0; d < D_MODEL; d += 4) {
    float4 zv = *(const float4*)&zr[d];
    acc0 = fmaf(zv.x, w[0 * D_MODEL + d], acc0); acc0 = fmaf(zv.y, w[0 * D_MODEL + d + 1], acc0);
    acc0 = fmaf(zv.z, w[0 * D_MODEL + d + 2], acc0); acc0 = fmaf(zv.w, w[0 * D_MODEL + d + 3], acc0);
    acc1 = fmaf(zv.x, w[1 * D_MODEL + d], acc1); acc1 = fmaf(zv.y, w[1 * D_MODEL + d + 1], acc1);
    acc1 = fmaf(zv.z, w[1 * D_MODEL + d + 2], acc1); acc1 = fmaf(zv.w, w[1 * D_MODEL + d + 3], acc1);
    acc2 = fmaf(zv.x, w[2 * D_MODEL + d], acc2); acc2 = fmaf(zv.y, w[2 * D_MODEL + d + 1], acc2);
    acc2 = fmaf(zv.z, w[2 * D_MODEL + d + 2], acc2); acc2 = fmaf(zv.w, w[2 * D_MODEL + d + 3], acc2);
    acc3 = fmaf(zv.x, w[3 * D_MODEL + d], acc3); acc3 = fmaf(zv.y, w[3 * D_MODEL + d + 1], acc3);
    acc3 = fmaf(zv.z, w[3 * D_MODEL + d + 2], acc3); acc3 = fmaf(zv.w, w[3 * D_MODEL + d + 3], acc3);
  }
  out[((size_t)b * OUTPUT_DIM + 0) * SEQLEN + l] = acc0;
  out[((size_t)b * OUTPUT_DIM + 1) * SEQLEN + l] = acc1;
  out[((size_t)b * OUTPUT_DIM + 2) * SEQLEN + l] = acc2;
  out[((size_t)b * OUTPUT_DIM + 3) * SEQLEN + l] = acc3;
}

/* ------------------------------- launch --------------------------------- */
extern "C" void kernel_launch(void* const* d_in, const int* in_sizes, int n_in,
                              void* d_out, int out_size, void* d_ws, size_t ws_size,
                              hipStream_t stream) {
  const float* inp       = (const float*)d_in[0];
  const float* lin_in_w  = (const float*)d_in[1];
  const float* lin_in_b  = (const float*)d_in[2];
  const float* in_w      = (const float*)d_in[3];
  const float* conv_w    = (const float*)d_in[4];
  const float* conv_b    = (const float*)d_in[5];
  const float* dt_bias   = (const float*)d_in[6];
  const float* A_log     = (const float*)d_in[7];
  const float* Dmat      = (const float*)d_in[8];
  const float* norm_w    = (const float*)d_in[9];
  const float* out_w     = (const float*)d_in[10];
  const float* ln_w      = (const float*)d_in[11];
  const float* ln_b      = (const float*)d_in[12];
  const float* lin_out_w = (const float*)d_in[13];
  const float* lin_out_b = (const float*)d_in[14];
  float* out = (float*)d_out;

  float* ws = (float*)d_ws;
  size_t off = 0;
  float* z      = ws + off; off += (size_t)ROWS * D_MODEL;
  float* zx     = ws + off; off += (size_t)ROWS * D_IN_PROJ;
  float* xc     = ws + off; off += (size_t)ROWS * CONV_DIM;
  float* y      = ws + off; off += (size_t)ROWS * D_INNER;
  float* tmp    = ws + off; off += (size_t)ROWS * D_MODEL;
  float* dtv    = ws + off; off += (size_t)BATCH * NHEADS * SEQLEN;
  float* cav    = ws + off; off += (size_t)BATCH * NHEADS * SEQLEN;
  float* Schunk = ws + off; off += (size_t)BATCH * NHEADS * NCHK * SSIZE;
  float* Sprev  = ws + off; off += (size_t)BATCH * NHEADS * NCHK * SSIZE;
  /* bf16 hi/lo operand buffers (ushort; element counts all multiples of 8) */
  unsigned short* zh  = (unsigned short*)(ws + off); off += (size_t)ROWS * D_MODEL / 2;
  unsigned short* zl  = (unsigned short*)(ws + off); off += (size_t)ROWS * D_MODEL / 2;
  unsigned short* yh  = (unsigned short*)(ws + off); off += (size_t)ROWS * D_INNER / 2;
  unsigned short* yl  = (unsigned short*)(ws + off); off += (size_t)ROWS * D_INNER / 2;
  unsigned short* wih = (unsigned short*)(ws + off); off += (size_t)NLAYERS * D_IN_PROJ * D_MODEL / 2;
  unsigned short* wil = (unsigned short*)(ws + off); off += (size_t)NLAYERS * D_IN_PROJ * D_MODEL / 2;
  unsigned short* woh = (unsigned short*)(ws + off); off += (size_t)NLAYERS * D_MODEL * D_INNER / 2;
  unsigned short* wol = (unsigned short*)(ws + off); off += (size_t)NLAYERS * D_MODEL * D_INNER / 2;

  const int n_iw = NLAYERS * D_IN_PROJ * D_MODEL;   /* 1,388,544 */
  const int n_ow = NLAYERS * D_MODEL * D_INNER;     /*   589,824 */
  k_cvt<<<(n_iw + 255) / 256, 256, 0, stream>>>(in_w, wih, wil, n_iw);
  k_cvt<<<(n_ow + 255) / 256, 256, 0, stream>>>(out_w, woh, wol, n_ow);
  k_lin_in<<<(ROWS * D_MODEL + 255) / 256, 256, 0, stream>>>(inp, lin_in_w, lin_in_b,
                                                             z, zh, zl);

  for (int i = 0; i < NLAYERS; i++) {
    k_gemm_mfma<<<dim3(ROWS / 128, (D_IN_PROJ + 63) / 64), 256, 0, stream>>>(
        zh, zl, wih + (size_t)i * D_IN_PROJ * D_MODEL, wil + (size_t)i * D_IN_PROJ * D_MODEL,
        zx, ROWS, D_IN_PROJ, D_MODEL);
    k_conv<<<(ROWS * CONV_DIM + 255) / 256, 256, 0, stream>>>(
        zx, conv_w + (size_t)i * CONV_DIM * D_CONV, conv_b + (size_t)i * CONV_DIM, xc);
    k_chunk1<<<BATCH * NHEADS * NCHK, 256, 0, stream>>>(
        z, in_w + (size_t)i * D_IN_PROJ * D_MODEL, xc,
        dt_bias + i * NHEADS, A_log + i * NHEADS, dtv, cav, Schunk);
    k_chunk2<<<BATCH * NHEADS * 12, 256, 0, stream>>>(cav, Schunk, Sprev);
    k_chunk3m<<<BATCH * NHEADS * NCHK, 256, 0, stream>>>(
        xc, dtv, cav, Sprev, Dmat + i * NHEADS, y);
    k_gate_rms<<<ROWS, 128, 0, stream>>>(y, zx, norm_w + (size_t)i * D_INNER, yh, yl);
    k_gemm_mfma<<<dim3(ROWS / 128, D_MODEL / 64), 256, 0, stream>>>(
        yh, yl, woh + (size_t)i * D_MODEL * D_INNER, wol + (size_t)i * D_MODEL * D_INNER,
        tmp, ROWS, D_MODEL, D_INNER);
    k_res_ln<<<ROWS, 64, 0, stream>>>(tmp, z, ln_w + (size_t)i * D_MODEL,
                                      ln_b + (size_t)i * D_MODEL, zh, zl);
  }

  k_lin_out<<<(ROWS + 255) / 256, 256, 0, stream>>>(z, lin_out_w, lin_out_b, out);
}